// Round 12
// baseline (47.100 us; speedup 1.0000x reference)
//
#include <hip/hip_runtime.h>

// CubeLens: radial lens deflection + bilinear gather + 4x4 avg pool.
// C=64, NS=256, NL=192, UPS=4. Output (64,192,192) fp32.
//
// R12: SINGLE kernel, direct fp32 gather from src (c,y,x). No transpose,
// no workspace. Insight: a channel's 4x4 corner patch = 4 contiguous
// f32x4 rows in the original layout (x fastest). Structure per block
// (32 px, 256 thr):
//   1A lane=(2px,tap): geometry; min/viol shfl butterflies; tap records
//      {dx,dy,wx,wy} -> LDS; gbase=(by0*256+bx0), gmode.
//   1B lane=(px,corner) x2: batched LDS tap-table reads -> corner wts
//      (pre-scaled by 1/16).
//   2  lane=(px,c8): per 4-channel batch, 16 f32x4 row loads (MLP 16),
//      then FMA against 16 hoisted weights. mode0=skip, mode2=per-tap.
//   epilogue: LDS repack -> nontemporal f32x4 coalesced stores.
//   XCD swizzle: blockIdx%8 -> contiguous pixel band per XCD.

#define NSRC 256
#define NLENS 192
#define NPIX (NLENS * NLENS)     // 36864
#define CSZ  64
#define PXB  32                  // pixels per block
#define NBLK (NPIX / PXB)        // 1152, divisible by 8
#define CH_STRIDE (NSRC * NSRC)  // 65536 floats per channel plane

typedef float f32x4  __attribute__((ext_vector_type(4)));
typedef float f32x4u __attribute__((ext_vector_type(4), aligned(4)));

struct Tap { int x0, y0; float wx, wy; bool inb; };

__device__ __forceinline__ Tap tapgeom(int p, int sub, float tE) {
    const int lx = p % NLENS, ly = p / NLENS;
    const float thy = ((float)(ly * 4 + (sub >> 2)) - 383.5f) * 0.01f;
    const float thx = ((float)(lx * 4 + (sub & 3))  - 383.5f) * 0.01f;
    const float r  = sqrtf(thx * thx + thy * thy) + 1e-8f;
    const float fx = (thx - (tE * thx) / r) / 0.02f + 127.5f;
    const float fy = (thy - (tE * thy) / r) / 0.02f + 127.5f;
    Tap tp;
    tp.inb = (fx >= 0.0f) & (fx <= 255.0f) & (fy >= 0.0f) & (fy <= 255.0f);
    tp.x0 = min(max((int)floorf(fx), 0), 254);
    tp.y0 = min(max((int)floorf(fy), 0), 254);
    tp.wx = fminf(fmaxf(fx - (float)tp.x0, 0.0f), 1.0f);
    tp.wy = fminf(fmaxf(fy - (float)tp.y0, 0.0f), 1.0f);
    return tp;
}

__global__ __launch_bounds__(256) void cubelens_direct(
    const float* __restrict__ src,      // (64,256,256) fp32
    const float* __restrict__ theta_p,
    float* __restrict__ out)            // (64,192,192) fp32
{
    __shared__ f32x4 Btap[PXB][16];     // per-tap {dx, dy, wx, wy}
    __shared__ float wpatch[PXB][16];   // per-pixel corner weights (pre /16)
    __shared__ int   gbase[PXB];        // by0*256 + bx0
    __shared__ int   gmode[PXB];        // 0=skip 1=patch 2=fallback
    __shared__ float smemO[CSZ][PXB + 1];

    const float tE = theta_p[0];
    const int b = blockIdx.x;
    const int pixblock = (b & 7) * (NBLK / 8) + (b >> 3);   // XCD swizzle
    const int p0 = pixblock * PXB;
    const int t  = threadIdx.x;

    // ---- phase 1A: tap geometry + patch base; lanes = (2px group, tap) ----
    {
        const int g = t >> 4, sub = t & 15;
#pragma unroll
        for (int h = 0; h < 2; ++h) {
            const int pi = 2 * g + h;
            const Tap tp = tapgeom(p0 + pi, sub, tE);
            const float x0f = (float)tp.x0, y0f = (float)tp.y0;
            float mnx = tp.inb ? x0f : 1e9f;
            float mny = tp.inb ? y0f : 1e9f;
#pragma unroll
            for (int off = 1; off < 16; off <<= 1) {
                mnx = fminf(mnx, __shfl_xor(mnx, off, 16));
                mny = fminf(mny, __shfl_xor(mny, off, 16));
            }
            const bool allout = (mnx > 5e8f);
            int viol = (tp.inb & ((x0f > mnx + 2.0f) | (y0f > mny + 2.0f))) ? 1 : 0;
#pragma unroll
            for (int off = 1; off < 16; off <<= 1)
                viol |= __shfl_xor(viol, off, 16);
            const float bxc = fminf(mnx, 252.0f);
            const float byc = fminf(mny, 252.0f);
            f32x4 rec;
            rec.x = tp.inb ? (x0f - bxc) : -1000.0f;
            rec.y = tp.inb ? (y0f - byc) : -1000.0f;
            rec.z = tp.wx;
            rec.w = tp.wy;
            Btap[pi][sub] = rec;
            if (sub == 0) {
                gbase[pi] = ((int)byc) * NSRC + (int)bxc;
                gmode[pi] = allout ? 0 : (viol ? 2 : 1);
            }
        }
    }
    __syncthreads();

    // ---- phase 1B: corner weights; lanes = (pixel, corner); 2 px/lane ----
    {
        const int sub = t & 15;
        const float cxf = (float)(sub & 3), cyf = (float)(sub >> 2);
#pragma unroll
        for (int h = 0; h < 2; ++h) {
            const int pi = (t >> 4) + 16 * h;
            float myw = 0.0f;
#pragma unroll
            for (int j = 0; j < 16; ++j) {
                const f32x4 r = Btap[pi][j];
                const float tx = cxf - r.x;        // in {0,1} iff corner hit
                const float ty = cyf - r.y;
                const float wxp = (tx == 0.0f) ? (1.0f - r.z)
                                : ((tx == 1.0f) ? r.z : 0.0f);
                const float wyp = (ty == 0.0f) ? (1.0f - r.w)
                                : ((ty == 1.0f) ? r.w : 0.0f);
                myw += wxp * wyp;
            }
            wpatch[pi][sub] = myw * 0.0625f;
        }
    }
    __syncthreads();

    // ---- phase 2: direct fp32 patch gather; thread = (pixel, c8) ----
    {
        const int pi2 = t >> 3, c8 = t & 7;       // channels 8*c8 .. 8*c8+7
        const int mode = gmode[pi2];
        float acc[8];
#pragma unroll
        for (int e = 0; e < 8; ++e) acc[e] = 0.0f;

        if (mode == 1) {
            // hoist the 16 weights (broadcast LDS reads)
            float w[16];
#pragma unroll
            for (int cn = 0; cn < 16; ++cn) w[cn] = wpatch[pi2][cn];

            const float* __restrict__ base =
                src + (size_t)(c8 * 8) * CH_STRIDE + gbase[pi2];
            // 2 batches of 4 channels; each batch = 16 f32x4 loads in flight
#pragma unroll
            for (int cb = 0; cb < 2; ++cb) {
                f32x4u rows[4][4];                 // [ch][dy]
#pragma unroll
                for (int ch = 0; ch < 4; ++ch)
#pragma unroll
                    for (int dy = 0; dy < 4; ++dy)
                        rows[ch][dy] = *(const f32x4u*)
                            (base + (size_t)(cb * 4 + ch) * CH_STRIDE + dy * NSRC);
#pragma unroll
                for (int ch = 0; ch < 4; ++ch)
#pragma unroll
                    for (int dy = 0; dy < 4; ++dy)
#pragma unroll
                        for (int dx = 0; dx < 4; ++dx)
                            acc[cb * 4 + ch] += w[dy * 4 + dx] * rows[ch][dy][dx];
            }
        } else if (mode == 2) {
            // rare wide-span pixel: per-tap gather straight from src
            for (int tap = 0; tap < 16; ++tap) {
                const Tap tp = tapgeom(p0 + pi2, tap, tE);
                if (tp.inb) {
                    const float w00 = (1.0f - tp.wy) * (1.0f - tp.wx);
                    const float w01 = (1.0f - tp.wy) * tp.wx;
                    const float w10 = tp.wy * (1.0f - tp.wx);
                    const float w11 = tp.wy * tp.wx;
                    const float* __restrict__ pp =
                        src + (size_t)(c8 * 8) * CH_STRIDE + tp.y0 * NSRC + tp.x0;
#pragma unroll
                    for (int ch = 0; ch < 8; ++ch) {
                        const float* __restrict__ pc = pp + (size_t)ch * CH_STRIDE;
                        acc[ch] += w00 * pc[0] + w01 * pc[1]
                                 + w10 * pc[NSRC] + w11 * pc[NSRC + 1];
                    }
                }
            }
#pragma unroll
            for (int e = 0; e < 8; ++e) acc[e] *= 0.0625f;
        }

#pragma unroll
        for (int e = 0; e < 8; ++e) smemO[c8 * 8 + e][pi2] = acc[e];
    }
    __syncthreads();

    // ---- epilogue: coalesced nontemporal f32x4 stores ----
    {
        const int c   = t >> 2;          // 0..63
        const int px8 = (t & 3) * 8;     // 0,8,16,24
        float* op = out + (size_t)c * NPIX + p0 + px8;
        f32x4 v0, v1;
        v0.x = smemO[c][px8 + 0]; v0.y = smemO[c][px8 + 1];
        v0.z = smemO[c][px8 + 2]; v0.w = smemO[c][px8 + 3];
        v1.x = smemO[c][px8 + 4]; v1.y = smemO[c][px8 + 5];
        v1.z = smemO[c][px8 + 6]; v1.w = smemO[c][px8 + 7];
        __builtin_nontemporal_store(v0, (f32x4*)op);
        __builtin_nontemporal_store(v1, (f32x4*)(op + 4));
    }
}

extern "C" void kernel_launch(void* const* d_in, const int* in_sizes, int n_in,
                              void* d_out, int out_size, void* d_ws, size_t ws_size,
                              hipStream_t stream) {
    const float* src   = (const float*)d_in[0];
    const float* theta = (const float*)d_in[1];
    float* out = (float*)d_out;
    cubelens_direct<<<dim3(NBLK), dim3(256), 0, stream>>>(src, theta, out);
}

// Round 13
// 29.582 us; speedup vs baseline: 1.5922x; 1.5922x over previous
//
#include <hip/hip_runtime.h>

// CubeLens: radial lens deflection + bilinear gather + 4x4 avg pool.
// C=64, NS=256, NL=192, UPS=4. Output (64,192,192) fp32.
//
// R13 = R11 (two-kernel, channel-last fp16 ws — R12 proved channel-last
// coalescing is essential) with WAVE-SYNCHRONOUS phases in the main
// kernel: wave w owns pixels 8w..8w+7 through 1A/1B/2, so the three
// block barriers become wave-local fences (lgkmcnt(0) + wave_barrier +
// sched_barrier). Only the epilogue repack keeps __syncthreads. Waves
// proceed independently -> ~18 independent pipelines/CU instead of 4.5
// lock-stepped blocks.
//   k1: fp32->fp16 channel-last transpose, XCD-swizzled.
//   k2: 1A lane=(2px,tap) geometry->Btap; wsync; issue 16 f16x8 corner
//       loads (T14); 1B weights (wave-local px map); wsync; FMA; barrier;
//       LDS repack -> nontemporal f32x4 stores. XCD swizzle.

#define NSRC 256
#define NLENS 192
#define NPIX (NLENS * NLENS)     // 36864
#define CSZ  64
#define PXB  32                  // pixels per block (8 per wave)
#define NBLK (NPIX / PXB)        // 1152, divisible by 8
#define NTTILE (NSRC * NSRC / 64)  // 1024 transpose tiles

typedef float    f32x4 __attribute__((ext_vector_type(4)));
typedef _Float16 f16x8 __attribute__((ext_vector_type(8)));

// wave-local LDS sync: drain LDS ops, then stop compiler/scheduler motion
#define WAVE_SYNC() do {                                   \
    asm volatile("s_waitcnt lgkmcnt(0)" ::: "memory");     \
    __builtin_amdgcn_wave_barrier();                       \
    __builtin_amdgcn_sched_barrier(0);                     \
} while (0)

// ---------------- fallback (round-1 kernel, used only if ws too small) ------
__global__ __launch_bounds__(256) void cubelens_fallback(
    const float* __restrict__ src, const float* __restrict__ theta_p,
    float* __restrict__ out)
{
    const float tE = theta_p[0];
    const int pix = blockIdx.x * 256 + threadIdx.x;
    const int c0  = blockIdx.y * 8;
    const int lx  = pix % NLENS;
    const int ly  = pix / NLENS;
    float acc[8];
#pragma unroll
    for (int c = 0; c < 8; ++c) acc[c] = 0.0f;
    const float* __restrict__ srcg = src + (size_t)c0 * (NSRC * NSRC);
#pragma unroll
    for (int uy = 0; uy < 4; ++uy) {
        const float thy = ((float)(ly * 4 + uy) - 383.5f) * 0.01f;
#pragma unroll
        for (int ux = 0; ux < 4; ++ux) {
            const float thx = ((float)(lx * 4 + ux) - 383.5f) * 0.01f;
            const float r  = sqrtf(thx * thx + thy * thy) + 1e-8f;
            const float fx = (thx - (tE * thx) / r) / 0.02f + 127.5f;
            const float fy = (thy - (tE * thy) / r) / 0.02f + 127.5f;
            const bool inb = (fx >= 0.0f) & (fx <= 255.0f) &
                             (fy >= 0.0f) & (fy <= 255.0f);
            if (!inb) continue;
            int x0 = min(max((int)floorf(fx), 0), 254);
            int y0 = min(max((int)floorf(fy), 0), 254);
            const float wx = fminf(fmaxf(fx - (float)x0, 0.0f), 1.0f);
            const float wy = fminf(fmaxf(fy - (float)y0, 0.0f), 1.0f);
            const float w00 = (1.0f - wy) * (1.0f - wx);
            const float w01 = (1.0f - wy) * wx;
            const float w10 = wy * (1.0f - wx);
            const float w11 = wy * wx;
            const float* __restrict__ p = srcg + y0 * NSRC + x0;
#pragma unroll
            for (int c = 0; c < 8; ++c) {
                const float* __restrict__ pc = p + c * (NSRC * NSRC);
                acc[c] += w00 * pc[0] + w01 * pc[1]
                        + w10 * pc[NSRC] + w11 * pc[NSRC + 1];
            }
        }
    }
#pragma unroll
    for (int c = 0; c < 8; ++c)
        out[(size_t)(c0 + c) * NPIX + pix] = acc[c] * 0.0625f;
}

// ---------------- k1: transpose (c,p) fp32 -> (p,c) fp16, XCD swizzle -------
__global__ __launch_bounds__(256) void transpose_kernel(
    const float* __restrict__ src, _Float16* __restrict__ ws)
{
    __shared__ float tile[CSZ][65];
    const int b = blockIdx.x;
    const int tileid = (b & 7) * (NTTILE / 8) + (b >> 3);
    const int p0 = tileid * 64;
    const int t  = threadIdx.x;
    {
        const int crow = t >> 4;
        const int px4  = (t & 15) * 4;
#pragma unroll
        for (int i = 0; i < 4; ++i) {
            const int c = crow + 16 * i;
            const f32x4 v = __builtin_nontemporal_load(
                (const f32x4*)(src + (size_t)c * (NSRC * NSRC) + p0 + px4));
            tile[c][px4 + 0] = v.x; tile[c][px4 + 1] = v.y;
            tile[c][px4 + 2] = v.z; tile[c][px4 + 3] = v.w;
        }
    }
    __syncthreads();
    {
        const int c8 = (t & 7) * 8;
        const int pr = t >> 3;
#pragma unroll
        for (int i = 0; i < 2; ++i) {
            const int p = pr + 32 * i;
            f16x8 h;
#pragma unroll
            for (int k = 0; k < 8; ++k) h[k] = (_Float16)tile[c8 + k][p];
            *(f16x8*)(ws + (size_t)(p0 + p) * CSZ + c8) = h;
        }
    }
}

// ---------------- k2: lens gather, wave-synchronous -------------------------
struct Tap { int x0, y0; float wx, wy; bool inb; };

__device__ __forceinline__ Tap tapgeom(int p, int sub, float tE) {
    const int lx = p % NLENS, ly = p / NLENS;
    const float thy = ((float)(ly * 4 + (sub >> 2)) - 383.5f) * 0.01f;
    const float thx = ((float)(lx * 4 + (sub & 3))  - 383.5f) * 0.01f;
    const float r  = sqrtf(thx * thx + thy * thy) + 1e-8f;
    const float fx = (thx - (tE * thx) / r) / 0.02f + 127.5f;
    const float fy = (thy - (tE * thy) / r) / 0.02f + 127.5f;
    Tap tp;
    tp.inb = (fx >= 0.0f) & (fx <= 255.0f) & (fy >= 0.0f) & (fy <= 255.0f);
    tp.x0 = min(max((int)floorf(fx), 0), 254);
    tp.y0 = min(max((int)floorf(fy), 0), 254);
    tp.wx = fminf(fmaxf(fx - (float)tp.x0, 0.0f), 1.0f);
    tp.wy = fminf(fmaxf(fy - (float)tp.y0, 0.0f), 1.0f);
    return tp;
}

__global__ __launch_bounds__(256) void cubelens_main(
    const _Float16* __restrict__ ws,    // (256,256,64) fp16
    const float* __restrict__ theta_p,
    float* __restrict__ out)            // (64,192,192) fp32
{
    __shared__ f32x4 Btap[PXB][16];
    __shared__ float wpatch[PXB][16];
    __shared__ int   gbase[PXB];
    __shared__ int   gmode[PXB];
    __shared__ float smemO[CSZ][PXB + 1];

    const float tE = theta_p[0];
    const int b = blockIdx.x;
    const int pixblock = (b & 7) * (NBLK / 8) + (b >> 3);   // XCD swizzle
    const int p0 = pixblock * PXB;
    const int t  = threadIdx.x;
    const int lane = t & 63;            // lane in wave
    const int wv   = t >> 6;            // wave id: owns pixels 8wv..8wv+7

    // ---- 1A: tap geometry; group g=(t>>4) -> pixels 2g,2g+1 (wave-local) --
    {
        const int g = t >> 4, sub = t & 15;
#pragma unroll
        for (int h = 0; h < 2; ++h) {
            const int pi = 2 * g + h;                  // in [8wv, 8wv+8)
            const Tap tp = tapgeom(p0 + pi, sub, tE);
            const float x0f = (float)tp.x0, y0f = (float)tp.y0;
            float mnx = tp.inb ? x0f : 1e9f;
            float mny = tp.inb ? y0f : 1e9f;
#pragma unroll
            for (int off = 1; off < 16; off <<= 1) {
                mnx = fminf(mnx, __shfl_xor(mnx, off, 16));
                mny = fminf(mny, __shfl_xor(mny, off, 16));
            }
            const bool allout = (mnx > 5e8f);
            int viol = (tp.inb & ((x0f > mnx + 2.0f) | (y0f > mny + 2.0f))) ? 1 : 0;
#pragma unroll
            for (int off = 1; off < 16; off <<= 1)
                viol |= __shfl_xor(viol, off, 16);
            const float bxc = fminf(mnx, 252.0f);
            const float byc = fminf(mny, 252.0f);
            f32x4 rec;
            rec.x = tp.inb ? (x0f - bxc) : -1000.0f;
            rec.y = tp.inb ? (y0f - byc) : -1000.0f;
            rec.z = tp.wx;
            rec.w = tp.wy;
            Btap[pi][sub] = rec;
            if (sub == 0) {
                gbase[pi] = (((int)byc) * NSRC + (int)bxc) * CSZ;
                gmode[pi] = allout ? 0 : (viol ? 2 : 1);
            }
        }
    }
    WAVE_SYNC();   // wave's own Btap/gbase/gmode visible to its lanes

    // ---- T14 issue-early: 16 corner loads for this thread's phase-2 px ----
    const int pi2 = t >> 3, c8 = t & 7;       // pi2 in [8wv, 8wv+8)
    const int mode2 = gmode[pi2];
    f16x8 v[16];
    if (mode2 == 1) {
        const _Float16* __restrict__ base = ws + gbase[pi2] + c8 * 8;
#pragma unroll
        for (int cn = 0; cn < 16; ++cn)
            v[cn] = *(const f16x8*)(base + ((cn >> 2) * NSRC + (cn & 3)) * CSZ);
    }

    // ---- 1B: corner weights while loads fly; wave-local pixel map ----
    {
        const int sub = t & 15;
        const float cxf = (float)(sub & 3), cyf = (float)(sub >> 2);
#pragma unroll
        for (int h = 0; h < 2; ++h) {
            const int pi = 8 * wv + 2 * (lane >> 4) + h;   // wave-local
            float myw = 0.0f;
#pragma unroll
            for (int j = 0; j < 16; ++j) {
                const f32x4 r = Btap[pi][j];
                const float tx = cxf - r.x;
                const float ty = cyf - r.y;
                const float wxp = (tx == 0.0f) ? (1.0f - r.z)
                                : ((tx == 1.0f) ? r.z : 0.0f);
                const float wyp = (ty == 0.0f) ? (1.0f - r.w)
                                : ((ty == 1.0f) ? r.w : 0.0f);
                myw += wxp * wyp;
            }
            wpatch[pi][sub] = myw * 0.0625f;
        }
    }
    WAVE_SYNC();   // wave's own wpatch visible

    // ---- phase 2: FMA on landed loads ----
    {
        float acc[8];
#pragma unroll
        for (int e = 0; e < 8; ++e) acc[e] = 0.0f;

        if (mode2 == 1) {
#pragma unroll
            for (int cn = 0; cn < 16; ++cn) {
                const float w = wpatch[pi2][cn];
#pragma unroll
                for (int e = 0; e < 8; ++e)
                    acc[e] += w * (float)v[cn][e];     // v_fma_mix_f32
            }
        } else if (mode2 == 2) {
            for (int tap = 0; tap < 16; ++tap) {
                const Tap tp = tapgeom(p0 + pi2, tap, tE);
                if (tp.inb) {
                    const _Float16* __restrict__ pp =
                        ws + (tp.y0 * NSRC + tp.x0) * CSZ + c8 * 8;
                    const f16x8 v00 = *(const f16x8*)(pp);
                    const f16x8 v01 = *(const f16x8*)(pp + CSZ);
                    const f16x8 v10 = *(const f16x8*)(pp + NSRC * CSZ);
                    const f16x8 v11 = *(const f16x8*)(pp + NSRC * CSZ + CSZ);
                    const float w00 = (1.0f - tp.wy) * (1.0f - tp.wx);
                    const float w01 = (1.0f - tp.wy) * tp.wx;
                    const float w10 = tp.wy * (1.0f - tp.wx);
                    const float w11 = tp.wy * tp.wx;
#pragma unroll
                    for (int e = 0; e < 8; ++e)
                        acc[e] += w00 * (float)v00[e] + w01 * (float)v01[e]
                                + w10 * (float)v10[e] + w11 * (float)v11[e];
                }
            }
#pragma unroll
            for (int e = 0; e < 8; ++e) acc[e] *= 0.0625f;
        }

#pragma unroll
        for (int e = 0; e < 8; ++e) smemO[c8 * 8 + e][pi2] = acc[e];
    }
    __syncthreads();   // epilogue reads all 32 px across waves

    // ---- epilogue: coalesced nontemporal f32x4 stores ----
    {
        const int c   = t >> 2;
        const int px8 = (t & 3) * 8;
        float* op = out + (size_t)c * NPIX + p0 + px8;
        f32x4 v0, v1;
        v0.x = smemO[c][px8 + 0]; v0.y = smemO[c][px8 + 1];
        v0.z = smemO[c][px8 + 2]; v0.w = smemO[c][px8 + 3];
        v1.x = smemO[c][px8 + 4]; v1.y = smemO[c][px8 + 5];
        v1.z = smemO[c][px8 + 6]; v1.w = smemO[c][px8 + 7];
        __builtin_nontemporal_store(v0, (f32x4*)op);
        __builtin_nontemporal_store(v1, (f32x4*)(op + 4));
    }
}

extern "C" void kernel_launch(void* const* d_in, const int* in_sizes, int n_in,
                              void* d_out, int out_size, void* d_ws, size_t ws_size,
                              hipStream_t stream) {
    const float* src   = (const float*)d_in[0];
    const float* theta = (const float*)d_in[1];
    float* out = (float*)d_out;

    const size_t need = (size_t)CSZ * NSRC * NSRC * sizeof(_Float16);  // 8.4 MB
    if (ws_size >= need) {
        _Float16* ws = (_Float16*)d_ws;
        transpose_kernel<<<dim3(NTTILE), dim3(256), 0, stream>>>(src, ws);
        cubelens_main<<<dim3(NBLK), dim3(256), 0, stream>>>(ws, theta, out);
    } else {
        cubelens_fallback<<<dim3(NPIX / 256, 8), dim3(256), 0, stream>>>(src, theta, out);
    }
}

// Round 14
// 29.399 us; speedup vs baseline: 1.6021x; 1.0062x over previous
//
#include <hip/hip_runtime.h>

// CubeLens: radial lens deflection + bilinear gather + 4x4 avg pool.
// C=64, NS=256, NL=192, UPS=4. Output (64,192,192) fp32.
//
// R14 = R13 + ONE change: __launch_bounds__(256, 3) on cubelens_main.
// Diagnosis: R12's profile showed VGPR_Count=60 while the kernel holds a
// 64-register corner array -> the compiler (bare launch_bounds(256) ->
// 8-waves/EU target, <=64 VGPR) was SPILLING the batched corner loads to
// scratch in every round since R4. The min-waves=3 hint (~168 VGPR cap)
// lets v[16] live in registers; 12 waves/CU still hides latency.

#define NSRC 256
#define NLENS 192
#define NPIX (NLENS * NLENS)     // 36864
#define CSZ  64
#define PXB  32                  // pixels per block (8 per wave)
#define NBLK (NPIX / PXB)        // 1152, divisible by 8
#define NTTILE (NSRC * NSRC / 64)  // 1024 transpose tiles

typedef float    f32x4 __attribute__((ext_vector_type(4)));
typedef _Float16 f16x8 __attribute__((ext_vector_type(8)));

// wave-local LDS sync: drain LDS ops, then stop compiler/scheduler motion
#define WAVE_SYNC() do {                                   \
    asm volatile("s_waitcnt lgkmcnt(0)" ::: "memory");     \
    __builtin_amdgcn_wave_barrier();                       \
    __builtin_amdgcn_sched_barrier(0);                     \
} while (0)

// ---------------- fallback (round-1 kernel, used only if ws too small) ------
__global__ __launch_bounds__(256) void cubelens_fallback(
    const float* __restrict__ src, const float* __restrict__ theta_p,
    float* __restrict__ out)
{
    const float tE = theta_p[0];
    const int pix = blockIdx.x * 256 + threadIdx.x;
    const int c0  = blockIdx.y * 8;
    const int lx  = pix % NLENS;
    const int ly  = pix / NLENS;
    float acc[8];
#pragma unroll
    for (int c = 0; c < 8; ++c) acc[c] = 0.0f;
    const float* __restrict__ srcg = src + (size_t)c0 * (NSRC * NSRC);
#pragma unroll
    for (int uy = 0; uy < 4; ++uy) {
        const float thy = ((float)(ly * 4 + uy) - 383.5f) * 0.01f;
#pragma unroll
        for (int ux = 0; ux < 4; ++ux) {
            const float thx = ((float)(lx * 4 + ux) - 383.5f) * 0.01f;
            const float r  = sqrtf(thx * thx + thy * thy) + 1e-8f;
            const float fx = (thx - (tE * thx) / r) / 0.02f + 127.5f;
            const float fy = (thy - (tE * thy) / r) / 0.02f + 127.5f;
            const bool inb = (fx >= 0.0f) & (fx <= 255.0f) &
                             (fy >= 0.0f) & (fy <= 255.0f);
            if (!inb) continue;
            int x0 = min(max((int)floorf(fx), 0), 254);
            int y0 = min(max((int)floorf(fy), 0), 254);
            const float wx = fminf(fmaxf(fx - (float)x0, 0.0f), 1.0f);
            const float wy = fminf(fmaxf(fy - (float)y0, 0.0f), 1.0f);
            const float w00 = (1.0f - wy) * (1.0f - wx);
            const float w01 = (1.0f - wy) * wx;
            const float w10 = wy * (1.0f - wx);
            const float w11 = wy * wx;
            const float* __restrict__ p = srcg + y0 * NSRC + x0;
#pragma unroll
            for (int c = 0; c < 8; ++c) {
                const float* __restrict__ pc = p + c * (NSRC * NSRC);
                acc[c] += w00 * pc[0] + w01 * pc[1]
                        + w10 * pc[NSRC] + w11 * pc[NSRC + 1];
            }
        }
    }
#pragma unroll
    for (int c = 0; c < 8; ++c)
        out[(size_t)(c0 + c) * NPIX + pix] = acc[c] * 0.0625f;
}

// ---------------- k1: transpose (c,p) fp32 -> (p,c) fp16, XCD swizzle -------
__global__ __launch_bounds__(256) void transpose_kernel(
    const float* __restrict__ src, _Float16* __restrict__ ws)
{
    __shared__ float tile[CSZ][65];
    const int b = blockIdx.x;
    const int tileid = (b & 7) * (NTTILE / 8) + (b >> 3);
    const int p0 = tileid * 64;
    const int t  = threadIdx.x;
    {
        const int crow = t >> 4;
        const int px4  = (t & 15) * 4;
#pragma unroll
        for (int i = 0; i < 4; ++i) {
            const int c = crow + 16 * i;
            const f32x4 v = __builtin_nontemporal_load(
                (const f32x4*)(src + (size_t)c * (NSRC * NSRC) + p0 + px4));
            tile[c][px4 + 0] = v.x; tile[c][px4 + 1] = v.y;
            tile[c][px4 + 2] = v.z; tile[c][px4 + 3] = v.w;
        }
    }
    __syncthreads();
    {
        const int c8 = (t & 7) * 8;
        const int pr = t >> 3;
#pragma unroll
        for (int i = 0; i < 2; ++i) {
            const int p = pr + 32 * i;
            f16x8 h;
#pragma unroll
            for (int k = 0; k < 8; ++k) h[k] = (_Float16)tile[c8 + k][p];
            *(f16x8*)(ws + (size_t)(p0 + p) * CSZ + c8) = h;
        }
    }
}

// ---------------- k2: lens gather, wave-synchronous -------------------------
struct Tap { int x0, y0; float wx, wy; bool inb; };

__device__ __forceinline__ Tap tapgeom(int p, int sub, float tE) {
    const int lx = p % NLENS, ly = p / NLENS;
    const float thy = ((float)(ly * 4 + (sub >> 2)) - 383.5f) * 0.01f;
    const float thx = ((float)(lx * 4 + (sub & 3))  - 383.5f) * 0.01f;
    const float r  = sqrtf(thx * thx + thy * thy) + 1e-8f;
    const float fx = (thx - (tE * thx) / r) / 0.02f + 127.5f;
    const float fy = (thy - (tE * thy) / r) / 0.02f + 127.5f;
    Tap tp;
    tp.inb = (fx >= 0.0f) & (fx <= 255.0f) & (fy >= 0.0f) & (fy <= 255.0f);
    tp.x0 = min(max((int)floorf(fx), 0), 254);
    tp.y0 = min(max((int)floorf(fy), 0), 254);
    tp.wx = fminf(fmaxf(fx - (float)tp.x0, 0.0f), 1.0f);
    tp.wy = fminf(fmaxf(fy - (float)tp.y0, 0.0f), 1.0f);
    return tp;
}

__global__ __launch_bounds__(256, 3) void cubelens_main(
    const _Float16* __restrict__ ws,    // (256,256,64) fp16
    const float* __restrict__ theta_p,
    float* __restrict__ out)            // (64,192,192) fp32
{
    __shared__ f32x4 Btap[PXB][16];
    __shared__ float wpatch[PXB][16];
    __shared__ int   gbase[PXB];
    __shared__ int   gmode[PXB];
    __shared__ float smemO[CSZ][PXB + 1];

    const float tE = theta_p[0];
    const int b = blockIdx.x;
    const int pixblock = (b & 7) * (NBLK / 8) + (b >> 3);   // XCD swizzle
    const int p0 = pixblock * PXB;
    const int t  = threadIdx.x;
    const int lane = t & 63;            // lane in wave
    const int wv   = t >> 6;            // wave id: owns pixels 8wv..8wv+7

    // ---- 1A: tap geometry; group g=(t>>4) -> pixels 2g,2g+1 (wave-local) --
    {
        const int g = t >> 4, sub = t & 15;
#pragma unroll
        for (int h = 0; h < 2; ++h) {
            const int pi = 2 * g + h;                  // in [8wv, 8wv+8)
            const Tap tp = tapgeom(p0 + pi, sub, tE);
            const float x0f = (float)tp.x0, y0f = (float)tp.y0;
            float mnx = tp.inb ? x0f : 1e9f;
            float mny = tp.inb ? y0f : 1e9f;
#pragma unroll
            for (int off = 1; off < 16; off <<= 1) {
                mnx = fminf(mnx, __shfl_xor(mnx, off, 16));
                mny = fminf(mny, __shfl_xor(mny, off, 16));
            }
            const bool allout = (mnx > 5e8f);
            int viol = (tp.inb & ((x0f > mnx + 2.0f) | (y0f > mny + 2.0f))) ? 1 : 0;
#pragma unroll
            for (int off = 1; off < 16; off <<= 1)
                viol |= __shfl_xor(viol, off, 16);
            const float bxc = fminf(mnx, 252.0f);
            const float byc = fminf(mny, 252.0f);
            f32x4 rec;
            rec.x = tp.inb ? (x0f - bxc) : -1000.0f;
            rec.y = tp.inb ? (y0f - byc) : -1000.0f;
            rec.z = tp.wx;
            rec.w = tp.wy;
            Btap[pi][sub] = rec;
            if (sub == 0) {
                gbase[pi] = (((int)byc) * NSRC + (int)bxc) * CSZ;
                gmode[pi] = allout ? 0 : (viol ? 2 : 1);
            }
        }
    }
    WAVE_SYNC();   // wave's own Btap/gbase/gmode visible to its lanes

    // ---- T14 issue-early: 16 corner loads for this thread's phase-2 px ----
    const int pi2 = t >> 3, c8 = t & 7;       // pi2 in [8wv, 8wv+8)
    const int mode2 = gmode[pi2];
    f16x8 v[16];
    if (mode2 == 1) {
        const _Float16* __restrict__ base = ws + gbase[pi2] + c8 * 8;
#pragma unroll
        for (int cn = 0; cn < 16; ++cn)
            v[cn] = *(const f16x8*)(base + ((cn >> 2) * NSRC + (cn & 3)) * CSZ);
    }

    // ---- 1B: corner weights while loads fly; wave-local pixel map ----
    {
        const int sub = t & 15;
        const float cxf = (float)(sub & 3), cyf = (float)(sub >> 2);
#pragma unroll
        for (int h = 0; h < 2; ++h) {
            const int pi = 8 * wv + 2 * (lane >> 4) + h;   // wave-local
            float myw = 0.0f;
#pragma unroll
            for (int j = 0; j < 16; ++j) {
                const f32x4 r = Btap[pi][j];
                const float tx = cxf - r.x;
                const float ty = cyf - r.y;
                const float wxp = (tx == 0.0f) ? (1.0f - r.z)
                                : ((tx == 1.0f) ? r.z : 0.0f);
                const float wyp = (ty == 0.0f) ? (1.0f - r.w)
                                : ((ty == 1.0f) ? r.w : 0.0f);
                myw += wxp * wyp;
            }
            wpatch[pi][sub] = myw * 0.0625f;
        }
    }
    WAVE_SYNC();   // wave's own wpatch visible

    // ---- phase 2: FMA on landed loads ----
    {
        float acc[8];
#pragma unroll
        for (int e = 0; e < 8; ++e) acc[e] = 0.0f;

        if (mode2 == 1) {
#pragma unroll
            for (int cn = 0; cn < 16; ++cn) {
                const float w = wpatch[pi2][cn];
#pragma unroll
                for (int e = 0; e < 8; ++e)
                    acc[e] += w * (float)v[cn][e];     // v_fma_mix_f32
            }
        } else if (mode2 == 2) {
            for (int tap = 0; tap < 16; ++tap) {
                const Tap tp = tapgeom(p0 + pi2, tap, tE);
                if (tp.inb) {
                    const _Float16* __restrict__ pp =
                        ws + (tp.y0 * NSRC + tp.x0) * CSZ + c8 * 8;
                    const f16x8 v00 = *(const f16x8*)(pp);
                    const f16x8 v01 = *(const f16x8*)(pp + CSZ);
                    const f16x8 v10 = *(const f16x8*)(pp + NSRC * CSZ);
                    const f16x8 v11 = *(const f16x8*)(pp + NSRC * CSZ + CSZ);
                    const float w00 = (1.0f - tp.wy) * (1.0f - tp.wx);
                    const float w01 = (1.0f - tp.wy) * tp.wx;
                    const float w10 = tp.wy * (1.0f - tp.wx);
                    const float w11 = tp.wy * tp.wx;
#pragma unroll
                    for (int e = 0; e < 8; ++e)
                        acc[e] += w00 * (float)v00[e] + w01 * (float)v01[e]
                                + w10 * (float)v10[e] + w11 * (float)v11[e];
                }
            }
#pragma unroll
            for (int e = 0; e < 8; ++e) acc[e] *= 0.0625f;
        }

#pragma unroll
        for (int e = 0; e < 8; ++e) smemO[c8 * 8 + e][pi2] = acc[e];
    }
    __syncthreads();   // epilogue reads all 32 px across waves

    // ---- epilogue: coalesced nontemporal f32x4 stores ----
    {
        const int c   = t >> 2;
        const int px8 = (t & 3) * 8;
        float* op = out + (size_t)c * NPIX + p0 + px8;
        f32x4 v0, v1;
        v0.x = smemO[c][px8 + 0]; v0.y = smemO[c][px8 + 1];
        v0.z = smemO[c][px8 + 2]; v0.w = smemO[c][px8 + 3];
        v1.x = smemO[c][px8 + 4]; v1.y = smemO[c][px8 + 5];
        v1.z = smemO[c][px8 + 6]; v1.w = smemO[c][px8 + 7];
        __builtin_nontemporal_store(v0, (f32x4*)op);
        __builtin_nontemporal_store(v1, (f32x4*)(op + 4));
    }
}

extern "C" void kernel_launch(void* const* d_in, const int* in_sizes, int n_in,
                              void* d_out, int out_size, void* d_ws, size_t ws_size,
                              hipStream_t stream) {
    const float* src   = (const float*)d_in[0];
    const float* theta = (const float*)d_in[1];
    float* out = (float*)d_out;

    const size_t need = (size_t)CSZ * NSRC * NSRC * sizeof(_Float16);  // 8.4 MB
    if (ws_size >= need) {
        _Float16* ws = (_Float16*)d_ws;
        transpose_kernel<<<dim3(NTTILE), dim3(256), 0, stream>>>(src, ws);
        cubelens_main<<<dim3(NBLK), dim3(256), 0, stream>>>(ws, theta, out);
    } else {
        cubelens_fallback<<<dim3(NPIX / 256, 8), dim3(256), 0, stream>>>(src, theta, out);
    }
}